// Round 1
// baseline (578.724 us; speedup 1.0000x reference)
//
#include <hip/hip_runtime.h>
#include <hip/hip_bf16.h>

#define NB   2
#define NH   16
#define SEQ  2048
#define DH   128

#define QB   64      // q rows per block
#define QW   16      // q rows per wave
#define KBLK 64      // kv per tile
#define KS   136     // K lds row stride (bf16 units), 272B: 16B-aligned, 2-way banks
#define VS   72      // V^T lds row stride (bf16), 144B: 16B-aligned, 2-way banks
#define PS   72      // P lds row stride

typedef short short8 __attribute__((ext_vector_type(8)));
typedef float f32x4  __attribute__((ext_vector_type(4)));

constexpr float INV_T = 0.08838834764831845f;   // 1/sqrt(128)
constexpr float LOG2E = 1.4426950408889634f;
constexpr float NEG   = -1e30f;

__device__ __forceinline__ unsigned short f2b(float x) {
    union { float f; unsigned u; } c; c.f = x;
    unsigned r = c.u + 0x7FFFu + ((c.u >> 16) & 1u);
    return (unsigned short)(r >> 16);
}

__global__ __launch_bounds__(256)
void attn_fwd(const float* __restrict__ Q, const float* __restrict__ K,
              const float* __restrict__ V, float* __restrict__ O)
{
    __shared__ __align__(16) unsigned short Ksh[KBLK * KS];
    __shared__ __align__(16) unsigned short Vsh[DH * VS];     // V^T: [d][kv]
    __shared__ __align__(16) unsigned short Psh[4][QW * PS];

    const int bid  = blockIdx.x;
    const int qblk = bid & 31;          // 32 q-blocks per head
    const int bh   = bid >> 5;          // B*H = 32
    const int tid  = threadIdx.x;
    const int wid  = tid >> 6;
    const int lane = tid & 63;
    const int l15  = lane & 15;
    const int l4   = lane >> 4;

    const size_t base  = (size_t)bh * SEQ * DH;
    const int    qbase = qblk * QB + wid * QW;

    // ---- Q fragments in registers, pre-scaled by 1/temperature ----
    // A-layout: lane holds A[row = lane&15][k = 8*(lane>>4) + j], j=0..7
    short8 aq[4];
    {
        const float* qp = Q + base + (size_t)(qbase + l15) * DH + 8 * l4;
        #pragma unroll
        for (int kb = 0; kb < 4; ++kb) {
            float4 x0 = *(const float4*)(qp + 32 * kb);
            float4 x1 = *(const float4*)(qp + 32 * kb + 4);
            short8 a;
            a[0] = (short)f2b(x0.x * INV_T); a[1] = (short)f2b(x0.y * INV_T);
            a[2] = (short)f2b(x0.z * INV_T); a[3] = (short)f2b(x0.w * INV_T);
            a[4] = (short)f2b(x1.x * INV_T); a[5] = (short)f2b(x1.y * INV_T);
            a[6] = (short)f2b(x1.z * INV_T); a[7] = (short)f2b(x1.w * INV_T);
            aq[kb] = a;
        }
    }

    f32x4 acc[8];
    #pragma unroll
    for (int i = 0; i < 8; ++i) acc[i] = (f32x4){0.f, 0.f, 0.f, 0.f};
    float mrun[4], lrun[4];
    #pragma unroll
    for (int j = 0; j < 4; ++j) { mrun[j] = NEG; lrun[j] = 0.f; }

    const int ntiles = qblk + 1;        // causal: kv tiles [0, qb+64)
    for (int t = 0; t < ntiles; ++t) {
        const int kvb = t * KBLK;

        // ---- stage K tile -> LDS (row-major, coalesced float4 reads) ----
        #pragma unroll
        for (int i = 0; i < 8; ++i) {
            int f  = tid + 256 * i;          // 2048 float4 in tile
            int kv = f >> 5, c4 = f & 31;
            float4 x = *(const float4*)(K + base + (size_t)(kvb + kv) * DH + 4 * c4);
            ushort4 b4;
            b4.x = f2b(x.x); b4.y = f2b(x.y); b4.z = f2b(x.z); b4.w = f2b(x.w);
            *(ushort4*)&Ksh[kv * KS + 4 * c4] = b4;
        }
        // ---- stage V^T tile -> LDS (column reads, contiguous-kv b128 writes) ----
        {
            const int dd  = tid & 127;
            const int kvg = (tid >> 7) * 8;
            #pragma unroll
            for (int p = 0; p < 4; ++p) {
                const int kvL = p * 16 + kvg;
                const float* vp = V + base + (size_t)(kvb + kvL) * DH + dd;
                float x[8];
                #pragma unroll
                for (int j = 0; j < 8; ++j) x[j] = vp[(size_t)j * DH];
                ushort4 lo, hi;
                lo.x = f2b(x[0]); lo.y = f2b(x[1]); lo.z = f2b(x[2]); lo.w = f2b(x[3]);
                hi.x = f2b(x[4]); hi.y = f2b(x[5]); hi.z = f2b(x[6]); hi.w = f2b(x[7]);
                *(ushort4*)&Vsh[dd * VS + kvL]     = lo;
                *(ushort4*)&Vsh[dd * VS + kvL + 4] = hi;
            }
        }
        __syncthreads();

        // ---- compute (skip if this wave's 16 rows are fully masked) ----
        if (kvb <= qbase + QW - 1) {
            // S-tile 16x64 = 4 col-blocks of 16x16
            f32x4 sf[4];
            #pragma unroll
            for (int f = 0; f < 4; ++f) {
                f32x4 c = (f32x4){0.f, 0.f, 0.f, 0.f};
                #pragma unroll
                for (int kb = 0; kb < 4; ++kb) {
                    short8 bk = *(const short8*)&Ksh[(16 * f + l15) * KS + 32 * kb + 8 * l4];
                    c = __builtin_amdgcn_mfma_f32_16x16x32_bf16(aq[kb], bk, c, 0, 0, 0);
                }
                sf[f] = c;
            }
            // mask (causal) + row max.  C/D: col = l15, row = 4*l4 + j
            float pmax[4] = {NEG, NEG, NEG, NEG};
            #pragma unroll
            for (int f = 0; f < 4; ++f) {
                const int col = kvb + 16 * f + l15;
                #pragma unroll
                for (int j = 0; j < 4; ++j) {
                    const int row = qbase + 4 * l4 + j;
                    float val = (col <= row) ? sf[f][j] : NEG;
                    sf[f][j] = val;
                    pmax[j] = fmaxf(pmax[j], val);
                }
            }
            #pragma unroll
            for (int j = 0; j < 4; ++j) {
                #pragma unroll
                for (int off = 8; off > 0; off >>= 1)
                    pmax[j] = fmaxf(pmax[j], __shfl_xor(pmax[j], off));
            }
            float scl[4], rsum[4];
            #pragma unroll
            for (int j = 0; j < 4; ++j) {
                float mn = fmaxf(mrun[j], pmax[j]);
                scl[j]  = exp2f((mrun[j] - mn) * LOG2E);
                mrun[j] = mn;
                rsum[j] = 0.f;
            }
            #pragma unroll
            for (int f = 0; f < 4; ++f) {
                #pragma unroll
                for (int j = 0; j < 4; ++j) {
                    float pv = exp2f((sf[f][j] - mrun[j]) * LOG2E);
                    sf[f][j] = pv;
                    rsum[j] += pv;
                }
            }
            #pragma unroll
            for (int j = 0; j < 4; ++j) {
                #pragma unroll
                for (int off = 8; off > 0; off >>= 1)
                    rsum[j] += __shfl_xor(rsum[j], off);
                lrun[j] = lrun[j] * scl[j] + rsum[j];
            }
            #pragma unroll
            for (int i = 0; i < 8; ++i)
                #pragma unroll
                for (int j = 0; j < 4; ++j)
                    acc[i][j] *= scl[j];

            // P -> LDS (re-enter A-fragment layout)
            #pragma unroll
            for (int f = 0; f < 4; ++f)
                #pragma unroll
                for (int j = 0; j < 4; ++j)
                    Psh[wid][(4 * l4 + j) * PS + 16 * f + l15] = f2b(sf[f][j]);

            // O += P @ V : A = P[16x64], B = V^T rows give B[k][col]
            #pragma unroll
            for (int kb = 0; kb < 2; ++kb) {
                short8 pa = *(const short8*)&Psh[wid][l15 * PS + 32 * kb + 8 * l4];
                #pragma unroll
                for (int db = 0; db < 8; ++db) {
                    short8 bv = *(const short8*)&Vsh[(16 * db + l15) * VS + 32 * kb + 8 * l4];
                    acc[db] = __builtin_amdgcn_mfma_f32_16x16x32_bf16(pa, bv, acc[db], 0, 0, 0);
                }
            }
        }
        __syncthreads();
    }

    // ---- epilogue: normalize by l, store fp32 ----
    float inv[4];
    #pragma unroll
    for (int j = 0; j < 4; ++j) inv[j] = 1.f / lrun[j];
    float* op = O + base + (size_t)qbase * DH;
    #pragma unroll
    for (int db = 0; db < 8; ++db)
        #pragma unroll
        for (int j = 0; j < 4; ++j)
            op[(size_t)(4 * l4 + j) * DH + 16 * db + l15] = acc[db][j] * inv[j];
}

extern "C" void kernel_launch(void* const* d_in, const int* in_sizes, int n_in,
                              void* d_out, int out_size, void* d_ws, size_t ws_size,
                              hipStream_t stream) {
    const float* q = (const float*)d_in[0];
    const float* k = (const float*)d_in[1];
    const float* v = (const float*)d_in[2];
    // d_in[3] = mask: deterministically causal (tril) -> applied analytically
    float* o = (float*)d_out;
    dim3 grid(NB * NH * (SEQ / QB));   // 1024
    dim3 block(256);
    attn_fwd<<<grid, block, 0, stream>>>(q, k, v, o);
}

// Round 2
// 248.516 us; speedup vs baseline: 2.3287x; 2.3287x over previous
//
#include <hip/hip_runtime.h>
#include <hip/hip_bf16.h>

#define NB   2
#define NH   16
#define NBH  (NB*NH)
#define SEQ  2048
#define DH   128

#define KBLK 64      // kv per tile
// legacy kernel params
#define QB   64
#define QW   16
#define KS   136
#define VS   72
#define PS   72

typedef short  short8    __attribute__((ext_vector_type(8)));
typedef unsigned short ushort8_t __attribute__((ext_vector_type(8)));
typedef float  f32x4     __attribute__((ext_vector_type(4)));

constexpr float INV_T = 0.08838834764831845f;   // 1/sqrt(128)
constexpr float LOG2E = 1.4426950408889634f;
constexpr float QSCL  = INV_T * LOG2E;          // fold log2e into Q scale
constexpr float NEG   = -1e30f;

__device__ __forceinline__ unsigned short f2b(float x) {
    union { float f; unsigned u; } c; c.f = x;
    unsigned r = c.u + 0x7FFFu + ((c.u >> 16) & 1u);
    return (unsigned short)(r >> 16);
}

__device__ __forceinline__ void gload_lds16(const void* g, void* l) {
    __builtin_amdgcn_global_load_lds(
        (const __attribute__((address_space(1))) unsigned int*)g,
        (__attribute__((address_space(3))) unsigned int*)l, 16, 0, 0);
}

// ---------------- prepass: K fp32 -> bf16 [bh][s][d] ----------------
__global__ __launch_bounds__(256)
void prep_k(const float* __restrict__ K, unsigned short* __restrict__ Kb) {
    size_t i = ((size_t)blockIdx.x * 256 + threadIdx.x) * 8;
    float4 a = *(const float4*)(K + i);
    float4 b = *(const float4*)(K + i + 4);
    ushort8_t o;
    o[0]=f2b(a.x); o[1]=f2b(a.y); o[2]=f2b(a.z); o[3]=f2b(a.w);
    o[4]=f2b(b.x); o[5]=f2b(b.y); o[6]=f2b(b.z); o[7]=f2b(b.w);
    *(ushort8_t*)(Kb + i) = o;
}

// ---------------- prepass: V fp32 [s][d] -> bf16 V^T [bh][d][s] ----------------
__global__ __launch_bounds__(256)
void prep_v(const float* __restrict__ V, unsigned short* __restrict__ Vt) {
    __shared__ unsigned short T[64][72];
    const int bid = blockIdx.x;
    const int dt = bid & 1, st = (bid >> 1) & 31, bh = bid >> 6;
    const int s0 = st * 64, d0 = dt * 64;
    const float* vb = V + (size_t)bh * SEQ * DH;
    const int tid = threadIdx.x;
    #pragma unroll
    for (int u = 0; u < 4; ++u) {
        int f = tid + 256 * u;
        int sl = f >> 4, c4 = f & 15;
        float4 x = *(const float4*)(vb + (size_t)(s0 + sl) * DH + d0 + c4 * 4);
        T[c4*4+0][sl] = f2b(x.x); T[c4*4+1][sl] = f2b(x.y);
        T[c4*4+2][sl] = f2b(x.z); T[c4*4+3][sl] = f2b(x.w);
    }
    __syncthreads();
    unsigned short* vo = Vt + (size_t)bh * DH * SEQ;
    const int dr = tid >> 2, ch = tid & 3;
    ushort8_t w0 = *(const ushort8_t*)&T[dr][ch*16];
    ushort8_t w1 = *(const ushort8_t*)&T[dr][ch*16 + 8];
    *(ushort8_t*)(vo + (size_t)(d0+dr)*SEQ + s0 + ch*16)     = w0;
    *(ushort8_t*)(vo + (size_t)(d0+dr)*SEQ + s0 + ch*16 + 8) = w1;
}

// ---------------- main: pair-folded causal flash attention ----------------
// block = 256 thr (4 waves), handles q-blocks {pair, 31-pair}: uniform 33 tiles.
// K lds [64][128] bf16, V^T lds [128][64] bf16, both XOR-swizzled via pre-swizzled
// global source (global_load_lds writes linearly). Double-buffered.
__global__ __launch_bounds__(256, 2)
void attn_fwd2(const float* __restrict__ Q,
               const unsigned short* __restrict__ Kb,
               const unsigned short* __restrict__ Vt,
               float* __restrict__ O)
{
    __shared__ __align__(16) unsigned short Ksh[2][64 * 128];
    __shared__ __align__(16) unsigned short Vsh[2][128 * 64];
    __shared__ __align__(16) unsigned short Psh[4][QW * PS];

    const int bid  = blockIdx.x;
    const int pair = bid & 15;
    const int bh   = bid >> 4;
    const int tid  = threadIdx.x;
    const int wid  = tid >> 6;
    const int lane = tid & 63;
    const int l15  = lane & 15;
    const int l4   = lane >> 4;
    const int rx   = l15 & 7;            // row&7 for all fragment rows (16f+l15)

    const size_t base = (size_t)bh * SEQ * DH;
    const unsigned short* Kbh = Kb + base;        // [s][d]
    const unsigned short* Vth = Vt + base;        // [d][s]

    // staging lambda: issue async global->LDS for tile tt into buffer bufi
    auto stage = [&](int bufi, int tt) {
        const int kv0 = tt * KBLK;
        {   // K: 64 rows x 256B; 4 instrs/wave, 4 rows each
            const int sl = lane & 15, rr = lane >> 4;
            #pragma unroll
            for (int i = 0; i < 4; ++i) {
                int row = wid * 16 + i * 4 + rr;
                int ss  = sl ^ (row & 7);
                gload_lds16(Kbh + (size_t)(kv0 + row) * DH + ss * 8,
                            &Ksh[bufi][(wid * 16 + i * 4) * 128]);
            }
        }
        {   // V^T: 128 rows x 128B; 4 instrs/wave, 8 rows each
            const int sl = lane & 7, rr = lane >> 3;
            #pragma unroll
            for (int i = 0; i < 4; ++i) {
                int row = wid * 32 + i * 8 + rr;
                int ss  = sl ^ (row & 7);
                gload_lds16(Vth + (size_t)row * SEQ + kv0 + ss * 8,
                            &Vsh[bufi][(wid * 32 + i * 8) * 64]);
            }
        }
    };

    for (int ph = 0; ph < 2; ++ph) {
        const int qblk  = ph ? (31 - pair) : pair;
        const int qbase = qblk * 64 + wid * QW;
        const int nt    = qblk + 1;

        // Q fragments in registers, scaled by (1/T)*log2e
        short8 aq[4];
        {
            const float* qp = Q + base + (size_t)(qbase + l15) * DH + 8 * l4;
            #pragma unroll
            for (int kb = 0; kb < 4; ++kb) {
                float4 x0 = *(const float4*)(qp + 32 * kb);
                float4 x1 = *(const float4*)(qp + 32 * kb + 4);
                short8 a;
                a[0] = (short)f2b(x0.x * QSCL); a[1] = (short)f2b(x0.y * QSCL);
                a[2] = (short)f2b(x0.z * QSCL); a[3] = (short)f2b(x0.w * QSCL);
                a[4] = (short)f2b(x1.x * QSCL); a[5] = (short)f2b(x1.y * QSCL);
                a[6] = (short)f2b(x1.z * QSCL); a[7] = (short)f2b(x1.w * QSCL);
                aq[kb] = a;
            }
        }

        f32x4 acc[8];
        #pragma unroll
        for (int i = 0; i < 8; ++i) acc[i] = (f32x4){0.f, 0.f, 0.f, 0.f};
        float mrun[4], lrun[4];
        #pragma unroll
        for (int j = 0; j < 4; ++j) { mrun[j] = NEG; lrun[j] = 0.f; }

        __syncthreads();                 // LDS safe to overwrite (prev phase done)
        stage(0, 0);

        for (int t = 0; t < nt; ++t) {
            const int cur = t & 1;
            const int kvb = t * KBLK;
            asm volatile("s_waitcnt vmcnt(0)" ::: "memory");
            __syncthreads();             // buf[cur] ready for whole block
            if (t + 1 < nt) stage(cur ^ 1, t + 1);   // overlap with compute

            if (kvb <= qbase + QW - 1) {
                const unsigned short* Kc = Ksh[cur];
                const unsigned short* Vc = Vsh[cur];

                // ---- QK^T: 16x64 S-tile ----
                f32x4 sf[4];
                #pragma unroll
                for (int f = 0; f < 4; ++f) {
                    f32x4 c = (f32x4){0.f, 0.f, 0.f, 0.f};
                    const int row = 16 * f + l15;
                    #pragma unroll
                    for (int kb = 0; kb < 4; ++kb) {
                        short8 bk = *(const short8*)&Kc[row * 128 + ((4 * kb + l4) ^ rx) * 8];
                        c = __builtin_amdgcn_mfma_f32_16x16x32_bf16(aq[kb], bk, c, 0, 0, 0);
                    }
                    sf[f] = c;
                }

                // ---- causal mask (diagonal tiles only) + row max ----
                float pmax[4] = {NEG, NEG, NEG, NEG};
                if (kvb + KBLK - 1 > qbase) {
                    #pragma unroll
                    for (int f = 0; f < 4; ++f) {
                        const int col = kvb + 16 * f + l15;
                        #pragma unroll
                        for (int j = 0; j < 4; ++j) {
                            const int row = qbase + 4 * l4 + j;
                            float val = (col <= row) ? sf[f][j] : NEG;
                            sf[f][j] = val;
                            pmax[j] = fmaxf(pmax[j], val);
                        }
                    }
                } else {
                    #pragma unroll
                    for (int f = 0; f < 4; ++f)
                        #pragma unroll
                        for (int j = 0; j < 4; ++j)
                            pmax[j] = fmaxf(pmax[j], sf[f][j]);
                }
                #pragma unroll
                for (int j = 0; j < 4; ++j) {
                    #pragma unroll
                    for (int off = 8; off > 0; off >>= 1)
                        pmax[j] = fmaxf(pmax[j], __shfl_xor(pmax[j], off));
                }
                float scl[4], rsum[4];
                #pragma unroll
                for (int j = 0; j < 4; ++j) {
                    float mn = fmaxf(mrun[j], pmax[j]);
                    scl[j]  = exp2f(mrun[j] - mn);
                    mrun[j] = mn;
                    rsum[j] = 0.f;
                }
                #pragma unroll
                for (int f = 0; f < 4; ++f) {
                    #pragma unroll
                    for (int j = 0; j < 4; ++j) {
                        float pv = exp2f(sf[f][j] - mrun[j]);
                        sf[f][j] = pv;
                        rsum[j] += pv;
                    }
                }
                #pragma unroll
                for (int j = 0; j < 4; ++j) {
                    #pragma unroll
                    for (int off = 8; off > 0; off >>= 1)
                        rsum[j] += __shfl_xor(rsum[j], off);
                    lrun[j] = lrun[j] * scl[j] + rsum[j];
                }
                #pragma unroll
                for (int i = 0; i < 8; ++i)
                    #pragma unroll
                    for (int j = 0; j < 4; ++j)
                        acc[i][j] *= scl[j];

                // ---- P -> LDS (A-fragment re-entry), padded stride ----
                #pragma unroll
                for (int f = 0; f < 4; ++f)
                    #pragma unroll
                    for (int j = 0; j < 4; ++j)
                        Psh[wid][(4 * l4 + j) * PS + 16 * f + l15] = f2b(sf[f][j]);

                // ---- O += P @ V ----
                #pragma unroll
                for (int kb = 0; kb < 2; ++kb) {
                    short8 pa = *(const short8*)&Psh[wid][l15 * PS + 32 * kb + 8 * l4];
                    #pragma unroll
                    for (int db = 0; db < 8; ++db) {
                        const int row = 16 * db + l15;
                        short8 bv = *(const short8*)&Vc[row * 64 + ((4 * kb + l4) ^ rx) * 8];
                        acc[db] = __builtin_amdgcn_mfma_f32_16x16x32_bf16(pa, bv, acc[db], 0, 0, 0);
                    }
                }
            }
        }

        // ---- epilogue ----
        float inv[4];
        #pragma unroll
        for (int j = 0; j < 4; ++j) inv[j] = 1.f / lrun[j];
        float* op = O + base + (size_t)qbase * DH;
        #pragma unroll
        for (int db = 0; db < 8; ++db)
            #pragma unroll
            for (int j = 0; j < 4; ++j)
                op[(size_t)(4 * l4 + j) * DH + 16 * db + l15] = acc[db][j] * inv[j];
    }
}

// ---------------- legacy fallback (round-1 kernel, used if ws too small) ----------------
__global__ __launch_bounds__(256)
void attn_fwd(const float* __restrict__ Q, const float* __restrict__ K,
              const float* __restrict__ V, float* __restrict__ O)
{
    __shared__ __align__(16) unsigned short KshL[KBLK * KS];
    __shared__ __align__(16) unsigned short VshL[DH * VS];
    __shared__ __align__(16) unsigned short PshL[4][QW * PS];

    const int bid  = blockIdx.x;
    const int qblk = bid & 31;
    const int bh   = bid >> 5;
    const int tid  = threadIdx.x;
    const int wid  = tid >> 6;
    const int lane = tid & 63;
    const int l15  = lane & 15;
    const int l4   = lane >> 4;

    const size_t base  = (size_t)bh * SEQ * DH;
    const int    qbase = qblk * QB + wid * QW;

    short8 aq[4];
    {
        const float* qp = Q + base + (size_t)(qbase + l15) * DH + 8 * l4;
        #pragma unroll
        for (int kb = 0; kb < 4; ++kb) {
            float4 x0 = *(const float4*)(qp + 32 * kb);
            float4 x1 = *(const float4*)(qp + 32 * kb + 4);
            short8 a;
            a[0] = (short)f2b(x0.x * INV_T); a[1] = (short)f2b(x0.y * INV_T);
            a[2] = (short)f2b(x0.z * INV_T); a[3] = (short)f2b(x0.w * INV_T);
            a[4] = (short)f2b(x1.x * INV_T); a[5] = (short)f2b(x1.y * INV_T);
            a[6] = (short)f2b(x1.z * INV_T); a[7] = (short)f2b(x1.w * INV_T);
            aq[kb] = a;
        }
    }
    f32x4 acc[8];
    #pragma unroll
    for (int i = 0; i < 8; ++i) acc[i] = (f32x4){0.f, 0.f, 0.f, 0.f};
    float mrun[4], lrun[4];
    #pragma unroll
    for (int j = 0; j < 4; ++j) { mrun[j] = NEG; lrun[j] = 0.f; }

    const int ntiles = qblk + 1;
    for (int t = 0; t < ntiles; ++t) {
        const int kvb = t * KBLK;
        #pragma unroll
        for (int i = 0; i < 8; ++i) {
            int f  = tid + 256 * i;
            int kv = f >> 5, c4 = f & 31;
            float4 x = *(const float4*)(K + base + (size_t)(kvb + kv) * DH + 4 * c4);
            ushort4 b4;
            b4.x = f2b(x.x); b4.y = f2b(x.y); b4.z = f2b(x.z); b4.w = f2b(x.w);
            *(ushort4*)&KshL[kv * KS + 4 * c4] = b4;
        }
        {
            const int dd  = tid & 127;
            const int kvg = (tid >> 7) * 8;
            #pragma unroll
            for (int p = 0; p < 4; ++p) {
                const int kvL = p * 16 + kvg;
                const float* vp = V + base + (size_t)(kvb + kvL) * DH + dd;
                float x[8];
                #pragma unroll
                for (int j = 0; j < 8; ++j) x[j] = vp[(size_t)j * DH];
                ushort4 lo, hi;
                lo.x = f2b(x[0]); lo.y = f2b(x[1]); lo.z = f2b(x[2]); lo.w = f2b(x[3]);
                hi.x = f2b(x[4]); hi.y = f2b(x[5]); hi.z = f2b(x[6]); hi.w = f2b(x[7]);
                *(ushort4*)&VshL[dd * VS + kvL]     = lo;
                *(ushort4*)&VshL[dd * VS + kvL + 4] = hi;
            }
        }
        __syncthreads();
        if (kvb <= qbase + QW - 1) {
            f32x4 sf[4];
            #pragma unroll
            for (int f = 0; f < 4; ++f) {
                f32x4 c = (f32x4){0.f, 0.f, 0.f, 0.f};
                #pragma unroll
                for (int kb = 0; kb < 4; ++kb) {
                    short8 bk = *(const short8*)&KshL[(16 * f + l15) * KS + 32 * kb + 8 * l4];
                    c = __builtin_amdgcn_mfma_f32_16x16x32_bf16(aq[kb], bk, c, 0, 0, 0);
                }
                sf[f] = c;
            }
            float pmax[4] = {NEG, NEG, NEG, NEG};
            #pragma unroll
            for (int f = 0; f < 4; ++f) {
                const int col = kvb + 16 * f + l15;
                #pragma unroll
                for (int j = 0; j < 4; ++j) {
                    const int row = qbase + 4 * l4 + j;
                    float val = (col <= row) ? sf[f][j] : NEG;
                    sf[f][j] = val;
                    pmax[j] = fmaxf(pmax[j], val);
                }
            }
            #pragma unroll
            for (int j = 0; j < 4; ++j) {
                #pragma unroll
                for (int off = 8; off > 0; off >>= 1)
                    pmax[j] = fmaxf(pmax[j], __shfl_xor(pmax[j], off));
            }
            float scl[4], rsum[4];
            #pragma unroll
            for (int j = 0; j < 4; ++j) {
                float mn = fmaxf(mrun[j], pmax[j]);
                scl[j]  = exp2f((mrun[j] - mn) * LOG2E);
                mrun[j] = mn;
                rsum[j] = 0.f;
            }
            #pragma unroll
            for (int f = 0; f < 4; ++f) {
                #pragma unroll
                for (int j = 0; j < 4; ++j) {
                    float pv = exp2f((sf[f][j] - mrun[j]) * LOG2E);
                    sf[f][j] = pv;
                    rsum[j] += pv;
                }
            }
            #pragma unroll
            for (int j = 0; j < 4; ++j) {
                #pragma unroll
                for (int off = 8; off > 0; off >>= 1)
                    rsum[j] += __shfl_xor(rsum[j], off);
                lrun[j] = lrun[j] * scl[j] + rsum[j];
            }
            #pragma unroll
            for (int i = 0; i < 8; ++i)
                #pragma unroll
                for (int j = 0; j < 4; ++j)
                    acc[i][j] *= scl[j];
            #pragma unroll
            for (int f = 0; f < 4; ++f)
                #pragma unroll
                for (int j = 0; j < 4; ++j)
                    PshL[wid][(4 * l4 + j) * PS + 16 * f + l15] = f2b(sf[f][j]);
            #pragma unroll
            for (int kb = 0; kb < 2; ++kb) {
                short8 pa = *(const short8*)&PshL[wid][l15 * PS + 32 * kb + 8 * l4];
                #pragma unroll
                for (int db = 0; db < 8; ++db) {
                    short8 bv = *(const short8*)&VshL[(16 * db + l15) * VS + 32 * kb + 8 * l4];
                    acc[db] = __builtin_amdgcn_mfma_f32_16x16x32_bf16(pa, bv, acc[db], 0, 0, 0);
                }
            }
        }
        __syncthreads();
    }
    float inv[4];
    #pragma unroll
    for (int j = 0; j < 4; ++j) inv[j] = 1.f / lrun[j];
    float* op = O + base + (size_t)qbase * DH;
    #pragma unroll
    for (int db = 0; db < 8; ++db)
        #pragma unroll
        for (int j = 0; j < 4; ++j)
            op[(size_t)(4 * l4 + j) * DH + 16 * db + l15] = acc[db][j] * inv[j];
}

extern "C" void kernel_launch(void* const* d_in, const int* in_sizes, int n_in,
                              void* d_out, int out_size, void* d_ws, size_t ws_size,
                              hipStream_t stream) {
    const float* q = (const float*)d_in[0];
    const float* k = (const float*)d_in[1];
    const float* v = (const float*)d_in[2];
    float* o = (float*)d_out;

    const size_t elems = (size_t)NBH * SEQ * DH;
    const size_t need  = elems * 2 * sizeof(unsigned short);   // Kbf + Vt, 33.5 MB
    if (ws_size >= need) {
        unsigned short* Kb = (unsigned short*)d_ws;
        unsigned short* Vt = Kb + elems;
        prep_k<<<dim3((unsigned)(elems / (256 * 8))), dim3(256), 0, stream>>>(k, Kb);
        prep_v<<<dim3(NBH * (SEQ / 64) * (DH / 64)), dim3(256), 0, stream>>>(v, Vt);
        attn_fwd2<<<dim3(NBH * 16), dim3(256), 0, stream>>>(q, Kb, Vt, o);
    } else {
        attn_fwd<<<dim3(NBH * 32), dim3(256), 0, stream>>>(q, k, v, o);
    }
}

// Round 4
// 240.173 us; speedup vs baseline: 2.4096x; 1.0347x over previous
//
#include <hip/hip_runtime.h>
#include <hip/hip_bf16.h>

#define NB   2
#define NH   16
#define NBH  (NB*NH)
#define SEQ  2048
#define DH   128

#define KBLK 64      // kv per tile
// legacy kernel params
#define QB   64
#define QW   16
#define KS   136
#define VS   72
#define PS   72

typedef short  short8    __attribute__((ext_vector_type(8)));
typedef unsigned short ushort8_t __attribute__((ext_vector_type(8)));
typedef float  f32x4     __attribute__((ext_vector_type(4)));
typedef int    int4v     __attribute__((ext_vector_type(4)));

constexpr float INV_T = 0.08838834764831845f;   // 1/sqrt(128)
constexpr float LOG2E = 1.4426950408889634f;
constexpr float QSCL  = INV_T * LOG2E;          // fold log2e into Q scale
constexpr float NEG   = -1e30f;
constexpr float DEFER = 8.0f;                   // defer-rescale threshold (log2 units)

__device__ __forceinline__ unsigned short f2b(float x) {
    union { float f; unsigned u; } c; c.f = x;
    unsigned r = c.u + 0x7FFFu + ((c.u >> 16) & 1u);
    return (unsigned short)(r >> 16);
}

__device__ __forceinline__ unsigned pack2(float lo, float hi) {
    return (unsigned)f2b(lo) | ((unsigned)f2b(hi) << 16);
}

__device__ __forceinline__ void gload_lds16(const void* g, void* l) {
    __builtin_amdgcn_global_load_lds(
        (const __attribute__((address_space(1))) unsigned int*)g,
        (__attribute__((address_space(3))) unsigned int*)l, 16, 0, 0);
}

// ---------------- prepass: K fp32 -> bf16 [bh][s][d] ----------------
__global__ __launch_bounds__(256)
void prep_k(const float* __restrict__ K, unsigned short* __restrict__ Kb) {
    size_t i = ((size_t)blockIdx.x * 256 + threadIdx.x) * 8;
    float4 a = *(const float4*)(K + i);
    float4 b = *(const float4*)(K + i + 4);
    ushort8_t o;
    o[0]=f2b(a.x); o[1]=f2b(a.y); o[2]=f2b(a.z); o[3]=f2b(a.w);
    o[4]=f2b(b.x); o[5]=f2b(b.y); o[6]=f2b(b.z); o[7]=f2b(b.w);
    *(ushort8_t*)(Kb + i) = o;
}

// ---------------- prepass: V fp32 [s][d] -> bf16 V^T [bh][d][s] ----------------
__global__ __launch_bounds__(256)
void prep_v(const float* __restrict__ V, unsigned short* __restrict__ Vt) {
    __shared__ unsigned short T[64][72];
    const int bid = blockIdx.x;
    const int dt = bid & 1, st = (bid >> 1) & 31, bh = bid >> 6;
    const int s0 = st * 64, d0 = dt * 64;
    const float* vb = V + (size_t)bh * SEQ * DH;
    const int tid = threadIdx.x;
    #pragma unroll
    for (int u = 0; u < 4; ++u) {
        int f = tid + 256 * u;
        int sl = f >> 4, c4 = f & 15;
        float4 x = *(const float4*)(vb + (size_t)(s0 + sl) * DH + d0 + c4 * 4);
        T[c4*4+0][sl] = f2b(x.x); T[c4*4+1][sl] = f2b(x.y);
        T[c4*4+2][sl] = f2b(x.z); T[c4*4+3][sl] = f2b(x.w);
    }
    __syncthreads();
    unsigned short* vo = Vt + (size_t)bh * DH * SEQ;
    const int dr = tid >> 2, ch = tid & 3;
    ushort8_t w0 = *(const ushort8_t*)&T[dr][ch*16];
    ushort8_t w1 = *(const ushort8_t*)&T[dr][ch*16 + 8];
    *(ushort8_t*)(vo + (size_t)(d0+dr)*SEQ + s0 + ch*16)     = w0;
    *(ushort8_t*)(vo + (size_t)(d0+dr)*SEQ + s0 + ch*16 + 8) = w1;
}

// ---------------- main: pair-folded causal flash attention ----------------
// Swapped-QK^T structure: S^T = mfma(K, Q) puts each q-row in one lane ->
// in-register softmax (2 shfl_xor reduces, scalar m/l), P stays in registers
// and is re-shaped into PV B-fragments with 16 shfl. PV: O^T = mfma(V^T, P).
__global__ __launch_bounds__(256, 2)
void attn_fwd2(const float* __restrict__ Q,
               const unsigned short* __restrict__ Kb,
               const unsigned short* __restrict__ Vt,
               float* __restrict__ O)
{
    __shared__ __align__(16) unsigned short Ksh[2][64 * 128];
    __shared__ __align__(16) unsigned short Vsh[2][128 * 64];

    const int bid  = blockIdx.x;
    const int pair = bid & 15;
    const int bh   = bid >> 4;
    const int tid  = threadIdx.x;
    const int wid  = tid >> 6;
    const int lane = tid & 63;
    const int l15  = lane & 15;
    const int l4   = lane >> 4;
    const int rx   = l15 & 7;            // row&7 for all fragment rows (16f+l15)
    const int hi   = l4 >> 1;
    const int srcA = l15 + 16 * ((2 * l4) & 3);
    const int srcB = l15 + 16 * ((2 * l4 + 1) & 3);

    const size_t base = (size_t)bh * SEQ * DH;
    const unsigned short* Kbh = Kb + base;        // [s][d]
    const unsigned short* Vth = Vt + base;        // [d][s]

    auto stage = [&](int bufi, int tt) {
        const int kv0 = tt * KBLK;
        {   // K: 64 rows x 256B
            const int sl = lane & 15, rr = lane >> 4;
            #pragma unroll
            for (int i = 0; i < 4; ++i) {
                int row = wid * 16 + i * 4 + rr;
                int ss  = sl ^ (row & 7);
                gload_lds16(Kbh + (size_t)(kv0 + row) * DH + ss * 8,
                            &Ksh[bufi][(wid * 16 + i * 4) * 128]);
            }
        }
        {   // V^T: 128 rows x 128B
            const int sl = lane & 7, rr = lane >> 3;
            #pragma unroll
            for (int i = 0; i < 4; ++i) {
                int row = wid * 32 + i * 8 + rr;
                int ss  = sl ^ (row & 7);
                gload_lds16(Vth + (size_t)row * SEQ + kv0 + ss * 8,
                            &Vsh[bufi][(wid * 32 + i * 8) * 64]);
            }
        }
    };

    for (int ph = 0; ph < 2; ++ph) {
        const int qblk  = ph ? (31 - pair) : pair;
        const int qbase = qblk * 64 + wid * QW;
        const int nt    = qblk + 1;
        const int qrow  = qbase + l15;      // this lane's q row

        // Q fragments (B-operand layout), scaled by (1/T)*log2e
        short8 aq[4];
        {
            const float* qp = Q + base + (size_t)qrow * DH + 8 * l4;
            #pragma unroll
            for (int kb = 0; kb < 4; ++kb) {
                float4 x0 = *(const float4*)(qp + 32 * kb);
                float4 x1 = *(const float4*)(qp + 32 * kb + 4);
                short8 a;
                a[0] = (short)f2b(x0.x * QSCL); a[1] = (short)f2b(x0.y * QSCL);
                a[2] = (short)f2b(x0.z * QSCL); a[3] = (short)f2b(x0.w * QSCL);
                a[4] = (short)f2b(x1.x * QSCL); a[5] = (short)f2b(x1.y * QSCL);
                a[6] = (short)f2b(x1.z * QSCL); a[7] = (short)f2b(x1.w * QSCL);
                aq[kb] = a;
            }
        }

        f32x4 acc[8];                       // O^T: acc[db][j] = O[qrow][16db+4l4+j]
        #pragma unroll
        for (int i = 0; i < 8; ++i) acc[i] = (f32x4){0.f, 0.f, 0.f, 0.f};
        float mrun = NEG, lrun = 0.f;

        __syncthreads();                    // LDS safe to overwrite
        stage(0, 0);

        for (int t = 0; t < nt; ++t) {
            const int cur = t & 1;
            const int kvb = t * KBLK;
            asm volatile("s_waitcnt vmcnt(0)" ::: "memory");
            __syncthreads();
            if (t + 1 < nt) stage(cur ^ 1, t + 1);

            const unsigned short* Kc = Ksh[cur];
            const unsigned short* Vc = Vsh[cur];

            // ---- S^T = K · Q^T  (64kv x 16q), lane: q=l15, kv=16f+4*l4+j ----
            f32x4 sf[4];
            __builtin_amdgcn_s_setprio(1);
            #pragma unroll
            for (int f = 0; f < 4; ++f) {
                f32x4 c = (f32x4){0.f, 0.f, 0.f, 0.f};
                const int row = 16 * f + l15;
                #pragma unroll
                for (int kb = 0; kb < 4; ++kb) {
                    short8 bk = *(const short8*)&Kc[row * 128 + ((4 * kb + l4) ^ rx) * 8];
                    c = __builtin_amdgcn_mfma_f32_16x16x32_bf16(bk, aq[kb], c, 0, 0, 0);
                }
                sf[f] = c;
            }
            __builtin_amdgcn_s_setprio(0);

            // ---- causal mask (diagonal tiles only) ----
            if (kvb + KBLK - 1 > qbase) {
                #pragma unroll
                for (int f = 0; f < 4; ++f) {
                    #pragma unroll
                    for (int j = 0; j < 4; ++j) {
                        const int kv = kvb + 16 * f + 4 * l4 + j;
                        if (kv > qrow) sf[f][j] = NEG;
                    }
                }
            }

            // ---- row max: local 16-tree + 2 shfl_xor ----
            float pmax;
            {
                float m0 = fmaxf(fmaxf(sf[0][0], sf[0][1]), fmaxf(sf[0][2], sf[0][3]));
                float m1 = fmaxf(fmaxf(sf[1][0], sf[1][1]), fmaxf(sf[1][2], sf[1][3]));
                float m2 = fmaxf(fmaxf(sf[2][0], sf[2][1]), fmaxf(sf[2][2], sf[2][3]));
                float m3 = fmaxf(fmaxf(sf[3][0], sf[3][1]), fmaxf(sf[3][2], sf[3][3]));
                pmax = fmaxf(fmaxf(m0, m1), fmaxf(m2, m3));
            }
            pmax = fmaxf(pmax, __shfl_xor(pmax, 16));
            pmax = fmaxf(pmax, __shfl_xor(pmax, 32));

            // ---- defer-rescale (T13): only rescale when max grew past threshold ----
            if (__any(pmax > mrun + DEFER)) {
                float mn  = fmaxf(mrun, pmax);
                float scl = exp2f(mrun - mn);
                mrun = mn;
                lrun *= scl;
                #pragma unroll
                for (int i = 0; i < 8; ++i)
                    #pragma unroll
                    for (int j = 0; j < 4; ++j)
                        acc[i][j] *= scl;
            }

            // ---- P = exp2(S - m), row sum ----
            float rs = 0.f;
            #pragma unroll
            for (int f = 0; f < 4; ++f)
                #pragma unroll
                for (int j = 0; j < 4; ++j) {
                    float p = exp2f(sf[f][j] - mrun);
                    sf[f][j] = p;
                    rs += p;
                }
            rs += __shfl_xor(rs, 16);
            rs += __shfl_xor(rs, 32);
            lrun += rs;

            // ---- pack P to bf16 dwords: pd[f] = {(j0,j1),(j2,j3)} ----
            unsigned pd0[4], pd1[4];
            #pragma unroll
            for (int f = 0; f < 4; ++f) {
                pd0[f] = pack2(sf[f][0], sf[f][1]);
                pd1[f] = pack2(sf[f][2], sf[f][3]);
            }

            // ---- PV: O^T += V^T · P^T, B-frag via shfl redistribution ----
            #pragma unroll
            for (int kb = 0; kb < 2; ++kb) {
                // dest lane needs source's pd[2kb+hi]; shuffle both, select by hi
                unsigned sA0 = __shfl(pd0[2*kb],     srcA);
                unsigned sA1 = __shfl(pd1[2*kb],     srcA);
                unsigned tA0 = __shfl(pd0[2*kb + 1], srcA);
                unsigned tA1 = __shfl(pd1[2*kb + 1], srcA);
                unsigned sB0 = __shfl(pd0[2*kb],     srcB);
                unsigned sB1 = __shfl(pd1[2*kb],     srcB);
                unsigned tB0 = __shfl(pd0[2*kb + 1], srcB);
                unsigned tB1 = __shfl(pd1[2*kb + 1], srcB);
                int4v w;
                w[0] = (int)(hi ? tA0 : sA0);
                w[1] = (int)(hi ? tA1 : sA1);
                w[2] = (int)(hi ? tB0 : sB0);
                w[3] = (int)(hi ? tB1 : sB1);
                short8 pb;
                __builtin_memcpy(&pb, &w, 16);

                __builtin_amdgcn_s_setprio(1);
                #pragma unroll
                for (int db = 0; db < 8; ++db) {
                    const int row = 16 * db + l15;
                    short8 bv = *(const short8*)&Vc[row * 64 + ((4 * kb + l4) ^ rx) * 8];
                    acc[db] = __builtin_amdgcn_mfma_f32_16x16x32_bf16(bv, pb, acc[db], 0, 0, 0);
                }
                __builtin_amdgcn_s_setprio(0);
            }
        }

        // ---- epilogue: O[qrow][16db+4l4+j] = acc/l, float4 stores ----
        const float inv = 1.f / lrun;
        float* op = O + base + (size_t)qrow * DH + 4 * l4;
        #pragma unroll
        for (int db = 0; db < 8; ++db) {
            float4 v;
            v.x = acc[db][0] * inv; v.y = acc[db][1] * inv;
            v.z = acc[db][2] * inv; v.w = acc[db][3] * inv;
            *(float4*)(op + 16 * db) = v;
        }
    }
}

// ---------------- legacy fallback (round-1 kernel, used if ws too small) ----------------
__global__ __launch_bounds__(256)
void attn_fwd(const float* __restrict__ Q, const float* __restrict__ K,
              const float* __restrict__ V, float* __restrict__ O)
{
    __shared__ __align__(16) unsigned short KshL[KBLK * KS];
    __shared__ __align__(16) unsigned short VshL[DH * VS];
    __shared__ __align__(16) unsigned short PshL[4][QW * PS];

    const int bid  = blockIdx.x;
    const int qblk = bid & 31;
    const int bh   = bid >> 5;
    const int tid  = threadIdx.x;
    const int wid  = tid >> 6;
    const int lane = tid & 63;
    const int l15  = lane & 15;
    const int l4   = lane >> 4;

    const size_t base  = (size_t)bh * SEQ * DH;
    const int    qbase = qblk * QB + wid * QW;

    short8 aq[4];
    {
        const float* qp = Q + base + (size_t)(qbase + l15) * DH + 8 * l4;
        #pragma unroll
        for (int kb = 0; kb < 4; ++kb) {
            float4 x0 = *(const float4*)(qp + 32 * kb);
            float4 x1 = *(const float4*)(qp + 32 * kb + 4);
            short8 a;
            a[0] = (short)f2b(x0.x * INV_T); a[1] = (short)f2b(x0.y * INV_T);
            a[2] = (short)f2b(x0.z * INV_T); a[3] = (short)f2b(x0.w * INV_T);
            a[4] = (short)f2b(x1.x * INV_T); a[5] = (short)f2b(x1.y * INV_T);
            a[6] = (short)f2b(x1.z * INV_T); a[7] = (short)f2b(x1.w * INV_T);
            aq[kb] = a;
        }
    }
    f32x4 acc[8];
    #pragma unroll
    for (int i = 0; i < 8; ++i) acc[i] = (f32x4){0.f, 0.f, 0.f, 0.f};
    float mrun[4], lrun[4];
    #pragma unroll
    for (int j = 0; j < 4; ++j) { mrun[j] = NEG; lrun[j] = 0.f; }

    const int ntiles = qblk + 1;
    for (int t = 0; t < ntiles; ++t) {
        const int kvb = t * KBLK;
        #pragma unroll
        for (int i = 0; i < 8; ++i) {
            int f  = tid + 256 * i;
            int kv = f >> 5, c4 = f & 31;
            float4 x = *(const float4*)(K + base + (size_t)(kvb + kv) * DH + 4 * c4);
            ushort4 b4;
            b4.x = f2b(x.x); b4.y = f2b(x.y); b4.z = f2b(x.z); b4.w = f2b(x.w);
            *(ushort4*)&KshL[kv * KS + 4 * c4] = b4;
        }
        {
            const int dd  = tid & 127;
            const int kvg = (tid >> 7) * 8;
            #pragma unroll
            for (int p = 0; p < 4; ++p) {
                const int kvL = p * 16 + kvg;
                const float* vp = V + base + (size_t)(kvb + kvL) * DH + dd;
                float x[8];
                #pragma unroll
                for (int j = 0; j < 8; ++j) x[j] = vp[(size_t)j * DH];
                ushort4 lo, hi;
                lo.x = f2b(x[0]); lo.y = f2b(x[1]); lo.z = f2b(x[2]); lo.w = f2b(x[3]);
                hi.x = f2b(x[4]); hi.y = f2b(x[5]); hi.z = f2b(x[6]); hi.w = f2b(x[7]);
                *(ushort4*)&VshL[dd * VS + kvL]     = lo;
                *(ushort4*)&VshL[dd * VS + kvL + 4] = hi;
            }
        }
        __syncthreads();
        if (kvb <= qbase + QW - 1) {
            f32x4 sf[4];
            #pragma unroll
            for (int f = 0; f < 4; ++f) {
                f32x4 c = (f32x4){0.f, 0.f, 0.f, 0.f};
                #pragma unroll
                for (int kb = 0; kb < 4; ++kb) {
                    short8 bk = *(const short8*)&KshL[(16 * f + l15) * KS + 32 * kb + 8 * l4];
                    c = __builtin_amdgcn_mfma_f32_16x16x32_bf16(aq[kb], bk, c, 0, 0, 0);
                }
                sf[f] = c;
            }
            float pmax[4] = {NEG, NEG, NEG, NEG};
            #pragma unroll
            for (int f = 0; f < 4; ++f) {
                const int col = kvb + 16 * f + l15;
                #pragma unroll
                for (int j = 0; j < 4; ++j) {
                    const int row = qbase + 4 * l4 + j;
                    float val = (col <= row) ? sf[f][j] : NEG;
                    sf[f][j] = val;
                    pmax[j] = fmaxf(pmax[j], val);
                }
            }
            #pragma unroll
            for (int j = 0; j < 4; ++j) {
                #pragma unroll
                for (int off = 8; off > 0; off >>= 1)
                    pmax[j] = fmaxf(pmax[j], __shfl_xor(pmax[j], off));
            }
            float scl[4], rsum[4];
            #pragma unroll
            for (int j = 0; j < 4; ++j) {
                float mn = fmaxf(mrun[j], pmax[j]);
                scl[j]  = exp2f((mrun[j] - mn) * LOG2E);
                mrun[j] = mn;
                rsum[j] = 0.f;
            }
            #pragma unroll
            for (int f = 0; f < 4; ++f) {
                #pragma unroll
                for (int j = 0; j < 4; ++j) {
                    float pv = exp2f((sf[f][j] - mrun[j]) * LOG2E);
                    sf[f][j] = pv;
                    rsum[j] += pv;
                }
            }
            #pragma unroll
            for (int j = 0; j < 4; ++j) {
                #pragma unroll
                for (int off = 8; off > 0; off >>= 1)
                    rsum[j] += __shfl_xor(rsum[j], off);
                lrun[j] = lrun[j] * scl[j] + rsum[j];
            }
            #pragma unroll
            for (int i = 0; i < 8; ++i)
                #pragma unroll
                for (int j = 0; j < 4; ++j)
                    acc[i][j] *= scl[j];
            #pragma unroll
            for (int f = 0; f < 4; ++f)
                #pragma unroll
                for (int j = 0; j < 4; ++j)
                    PshL[wid][(4 * l4 + j) * PS + 16 * f + l15] = f2b(sf[f][j]);
            #pragma unroll
            for (int kb = 0; kb < 2; ++kb) {
                short8 pa = *(const short8*)&PshL[wid][l15 * PS + 32 * kb + 8 * l4];
                #pragma unroll
                for (int db = 0; db < 8; ++db) {
                    short8 bv = *(const short8*)&VshL[(16 * db + l15) * VS + 32 * kb + 8 * l4];
                    acc[db] = __builtin_amdgcn_mfma_f32_16x16x32_bf16(pa, bv, acc[db], 0, 0, 0);
                }
            }
        }
        __syncthreads();
    }
    float inv[4];
    #pragma unroll
    for (int j = 0; j < 4; ++j) inv[j] = 1.f / lrun[j];
    float* op = O + base + (size_t)qbase * DH;
    #pragma unroll
    for (int db = 0; db < 8; ++db)
        #pragma unroll
        for (int j = 0; j < 4; ++j)
            op[(size_t)(4 * l4 + j) * DH + 16 * db + l15] = acc[db][j] * inv[j];
}

extern "C" void kernel_launch(void* const* d_in, const int* in_sizes, int n_in,
                              void* d_out, int out_size, void* d_ws, size_t ws_size,
                              hipStream_t stream) {
    const float* q = (const float*)d_in[0];
    const float* k = (const float*)d_in[1];
    const float* v = (const float*)d_in[2];
    float* o = (float*)d_out;

    const size_t elems = (size_t)NBH * SEQ * DH;
    const size_t need  = elems * 2 * sizeof(unsigned short);   // Kbf + Vt, 33.5 MB
    if (ws_size >= need) {
        unsigned short* Kb = (unsigned short*)d_ws;
        unsigned short* Vt = Kb + elems;
        prep_k<<<dim3((unsigned)(elems / (256 * 8))), dim3(256), 0, stream>>>(k, Kb);
        prep_v<<<dim3(NBH * (SEQ / 64) * (DH / 64)), dim3(256), 0, stream>>>(v, Vt);
        attn_fwd2<<<dim3(NBH * 16), dim3(256), 0, stream>>>(q, Kb, Vt, o);
    } else {
        attn_fwd<<<dim3(NBH * 32), dim3(256), 0, stream>>>(q, k, v, o);
    }
}